// Round 1
// baseline (86403.973 us; speedup 1.0000x reference)
//
#include <hip/hip_runtime.h>
#include <math.h>

#define B_ 2048
#define T_ 100
#define V_ 20000
#define NCA 128
#define CH_A 157   // 128*157 = 20096 >= 20000
#define NCB 64
#define CH_B 313   // 64*313 = 20032 >= 20000

// KT[v*T+t] = exp(-M[t*V+v]*lam); KMT = KT*M  (tiled transpose via LDS)
__global__ void k_initK(const float* __restrict__ M, const int* __restrict__ alpha,
                        float* __restrict__ KT, float* __restrict__ KMT) {
    __shared__ float tile[32][33];
    float lam = (float)(*alpha);
    int v0 = blockIdx.x * 32;
    int t0 = blockIdx.y * 32;
    int tx = threadIdx.x, ty = threadIdx.y;
    for (int j = 0; j < 4; ++j) {
        int t = t0 + ty + 8 * j;
        tile[ty + 8 * j][tx] = (t < T_) ? M[(size_t)t * V_ + v0 + tx] : 0.f;
    }
    __syncthreads();
    for (int j = 0; j < 4; ++j) {
        int t = t0 + tx;
        int v = v0 + ty + 8 * j;
        if (t < T_) {
            float m = tile[tx][ty + 8 * j];
            float k = __expf(-m * lam);
            KT[(size_t)v * T_ + t] = k;
            KMT[(size_t)v * T_ + t] = k * m;
        }
    }
}

// u init, dtT transpose, s1 row sums, zero rec accumulators
__global__ void k_init2(const float* __restrict__ dt, float* __restrict__ u,
                        float* __restrict__ dtT, float* __restrict__ s1,
                        float* __restrict__ recSE, float* __restrict__ recSXL,
                        float* __restrict__ recSX) {
    int i = blockIdx.x * 256 + threadIdx.x;
    if (i < T_ * B_) {
        u[i] = 1.0f / T_;
        int t = i / B_, b = i % B_;
        dtT[i] = dt[(size_t)b * T_ + t];
    }
    if (i < B_) {
        float s = 0.f;
        for (int t = 0; t < T_; ++t) s += dt[(size_t)i * T_ + t];
        s1[i] = s;
        recSE[i] = 0.f; recSXL[i] = 0.f; recSX[i] = 0.f;
    }
}

// bwT[v*B+b] = dw[b*V+v]  (tiled transpose)
__global__ void k_transpose(const float* __restrict__ in, float* __restrict__ outT) {
    __shared__ float tile[32][33];
    int v0 = blockIdx.x * 32, b0 = blockIdx.y * 32;
    int tx = threadIdx.x, ty = threadIdx.y;
    for (int j = 0; j < 4; ++j)
        tile[ty + 8 * j][tx] = in[(size_t)(b0 + ty + 8 * j) * V_ + v0 + tx];
    __syncthreads();
    for (int j = 0; j < 4; ++j)
        outT[(size_t)(v0 + ty + 8 * j) * B_ + b0 + tx] = tile[tx][ty + 8 * j];
}

// vbuf[v,b] = bwT[v,b] / sum_t KT[v,t]*u[t,b]
__global__ void k_A(const float* __restrict__ KT, const float* __restrict__ u,
                    const float* __restrict__ bwT, float* __restrict__ vbuf) {
    int b = blockIdx.x * 256 + threadIdx.x;
    int c = blockIdx.y;
    int v0 = c * CH_A;
    int v1 = min(V_, v0 + CH_A);
    float ur[T_];
#pragma unroll
    for (int t = 0; t < T_; ++t) ur[t] = u[(size_t)t * B_ + b];
    for (int v = v0; v < v1; ++v) {
        const float* kr = KT + (size_t)v * T_;
        float d0 = 0.f, d1 = 0.f, d2 = 0.f, d3 = 0.f;
#pragma unroll
        for (int t = 0; t < T_; t += 4) {
            d0 += kr[t] * ur[t];
            d1 += kr[t + 1] * ur[t + 1];
            d2 += kr[t + 2] * ur[t + 2];
            d3 += kr[t + 3] * ur[t + 3];
        }
        float den = (d0 + d1) + (d2 + d3);
        vbuf[(size_t)v * B_ + b] = bwT[(size_t)v * B_ + b] / den;
    }
}

// part[c][t][b] = sum_{v in chunk c} Kmat[v,t]*vbuf[v,b]
__global__ void k_B1(const float* __restrict__ Kmat, const float* __restrict__ vbuf,
                     float* __restrict__ part) {
    int b = blockIdx.x * 256 + threadIdx.x;
    int c = blockIdx.y;
    int v0 = c * CH_B;
    int v1 = min(V_, v0 + CH_B);
    float acc[T_];
#pragma unroll
    for (int t = 0; t < T_; ++t) acc[t] = 0.f;
    for (int v = v0; v < v1; ++v) {
        float vv = vbuf[(size_t)v * B_ + b];
        const float* kr = Kmat + (size_t)v * T_;
#pragma unroll
        for (int t = 0; t < T_; ++t) acc[t] += kr[t] * vv;
    }
#pragma unroll
    for (int t = 0; t < T_; ++t)
        part[((size_t)c * T_ + t) * B_ + b] = acc[t];
}

// reduce partials; mode 0: out = dtT/sum (u update); mode 1: out = sum (kmv)
__global__ void k_B2(const float* __restrict__ part, const float* __restrict__ dtT,
                     float* __restrict__ out, int mode) {
    int i = blockIdx.x * 256 + threadIdx.x;
    if (i >= T_ * B_) return;
    float s = 0.f;
    for (int c = 0; c < NCB; ++c) s += part[(size_t)c * T_ * B_ + i];
    out[i] = mode ? s : dtT[i] / s;
}

// div[b] = sum_t u[t,b]*kmv[t,b]
__global__ void k_div(const float* __restrict__ u, const float* __restrict__ kmv,
                      float* __restrict__ divb) {
    int b = blockIdx.x * 256 + threadIdx.x;
    if (b >= B_) return;
    float s = 0.f;
    for (int t = 0; t < T_; ++t) s += u[(size_t)t * B_ + b] * kmv[(size_t)t * B_ + b];
    divb[b] = s;
}

// reconstruction-loss accumulators: per b, sum over v of exp(logit), logit*x, x
__global__ void k_rec(const float* __restrict__ M, const float* __restrict__ dt,
                      const float* __restrict__ x, const float* __restrict__ s1,
                      float* __restrict__ recSE, float* __restrict__ recSXL,
                      float* __restrict__ recSX) {
    int v = blockIdx.x * 256 + threadIdx.x;
    int b0 = blockIdx.y * 256;
    bool act = v < V_;
    float Mreg[T_];
#pragma unroll
    for (int t = 0; t < T_; ++t) Mreg[t] = act ? M[(size_t)t * V_ + v] : 0.f;
    for (int bb = 0; bb < 256; ++bb) {
        int b = b0 + bb;
        const float* dtr = dt + (size_t)b * T_;
        float g0 = 0.f, g1 = 0.f, g2 = 0.f, g3 = 0.f;
#pragma unroll
        for (int t = 0; t < T_; t += 4) {
            g0 += dtr[t] * Mreg[t];
            g1 += dtr[t + 1] * Mreg[t + 1];
            g2 += dtr[t + 2] * Mreg[t + 2];
            g3 += dtr[t + 3] * Mreg[t + 3];
        }
        float logit = s1[b] - ((g0 + g1) + (g2 + g3));
        float xv = act ? x[(size_t)b * V_ + v] : 0.f;
        float e = act ? __expf(logit) : 0.f;
        float r0 = e, r1 = logit * xv, r2 = xv;
#pragma unroll
        for (int off = 32; off > 0; off >>= 1) {
            r0 += __shfl_down(r0, off, 64);
            r1 += __shfl_down(r1, off, 64);
            r2 += __shfl_down(r2, off, 64);
        }
        if ((threadIdx.x & 63) == 0) {
            atomicAdd(&recSE[b], r0);
            atomicAdd(&recSXL[b], r1);
            atomicAdd(&recSX[b], r2);
        }
    }
}

__global__ void k_final(const float* __restrict__ divb, const float* __restrict__ recSE,
                        const float* __restrict__ recSXL, const float* __restrict__ recSX,
                        const int* __restrict__ wptr, float* __restrict__ out) {
    __shared__ float sA[256], sB[256];
    int tid = threadIdx.x;
    float accS = 0.f, accR = 0.f;
    for (int b = tid; b < B_; b += 256) {
        accS += divb[b];
        accR += recSXL[b] - logf(recSE[b]) * recSX[b];
    }
    sA[tid] = accS; sB[tid] = accR;
    __syncthreads();
    for (int s = 128; s > 0; s >>= 1) {
        if (tid < s) { sA[tid] += sA[tid + s]; sB[tid] += sB[tid + s]; }
        __syncthreads();
    }
    if (tid == 0) {
        float sh = sA[0] / (float)B_;
        float rec = -sB[0] / (float)B_;
        out[0] = rec;
        out[1] = sh;
        out[2] = (float)(*wptr) * rec + sh;
    }
}

extern "C" void kernel_launch(void* const* d_in, const int* in_sizes, int n_in,
                              void* d_out, int out_size, void* d_ws, size_t ws_size,
                              hipStream_t stream) {
    const float* x  = (const float*)d_in[0];
    const float* dt = (const float*)d_in[1];
    const float* dw = (const float*)d_in[2];
    const float* M  = (const float*)d_in[3];
    const int* alpha = (const int*)d_in[5];
    const int* wrec  = (const int*)d_in[6];
    float* out = (float*)d_out;

    float* ws = (float*)d_ws;
    float* KT     = ws;                       // 2,000,000
    float* KMT    = KT + 2000000;             // 2,000,000
    float* dtT    = KMT + 2000000;            // 204,800
    float* u      = dtT + 204800;             // 204,800
    float* s1     = u + 204800;               // 2,048
    float* recSE  = s1 + 2048;                // 2,048
    float* recSXL = recSE + 2048;             // 2,048
    float* recSX  = recSXL + 2048;            // 2,048
    float* divb   = recSX + 2048;             // 2,048
    float* kmv    = divb + 2048;              // 204,800
    float* part   = kmv + 204800;             // 64*100*2048 = 13,107,200
    float* bwT    = part + (size_t)NCB * T_ * B_;   // 40,960,000
    float* vbuf   = bwT + (size_t)V_ * B_;          // 40,960,000

    dim3 blk32(32, 8);
    k_initK<<<dim3(625, 4), blk32, 0, stream>>>(M, alpha, KT, KMT);
    k_init2<<<(T_ * B_ + 255) / 256, 256, 0, stream>>>(dt, u, dtT, s1, recSE, recSXL, recSX);
    k_transpose<<<dim3(625, 64), blk32, 0, stream>>>(dw, bwT);
    k_rec<<<dim3(79, 8), 256, 0, stream>>>(M, dt, x, s1, recSE, recSXL, recSX);

    for (int it = 0; it < 50; ++it) {
        k_A<<<dim3(8, NCA), 256, 0, stream>>>(KT, u, bwT, vbuf);
        k_B1<<<dim3(8, NCB), 256, 0, stream>>>(KT, vbuf, part);
        k_B2<<<(T_ * B_ + 255) / 256, 256, 0, stream>>>(part, dtT, u, 0);
    }
    k_A<<<dim3(8, NCA), 256, 0, stream>>>(KT, u, bwT, vbuf);
    k_B1<<<dim3(8, NCB), 256, 0, stream>>>(KMT, vbuf, part);
    k_B2<<<(T_ * B_ + 255) / 256, 256, 0, stream>>>(part, dtT, kmv, 1);
    k_div<<<(B_ + 255) / 256, 256, 0, stream>>>(u, kmv, divb);
    k_final<<<1, 256, 0, stream>>>(divb, recSE, recSXL, recSX, wrec, out);
}

// Round 2
// 23102.074 us; speedup vs baseline: 3.7401x; 3.7401x over previous
//
#include <hip/hip_runtime.h>
#include <math.h>

#define B_ 2048
#define T_ 100
#define V_ 20000
#define NC 64
#define CH 313   // 64*313 = 20032 >= 20000

// KT[v*T+t] = exp(-M[t*V+v]*lam); KMT = KT*M  (tiled transpose via LDS)
__global__ void k_initK(const float* __restrict__ M, const int* __restrict__ alpha,
                        float* __restrict__ KT, float* __restrict__ KMT) {
    __shared__ float tile[32][33];
    float lam = (float)(*alpha);
    int v0 = blockIdx.x * 32;
    int t0 = blockIdx.y * 32;
    int tx = threadIdx.x, ty = threadIdx.y;
    for (int j = 0; j < 4; ++j) {
        int t = t0 + ty + 8 * j;
        tile[ty + 8 * j][tx] = (t < T_) ? M[(size_t)t * V_ + v0 + tx] : 0.f;
    }
    __syncthreads();
    for (int j = 0; j < 4; ++j) {
        int t = t0 + tx;
        int v = v0 + ty + 8 * j;
        if (t < T_) {
            float m = tile[tx][ty + 8 * j];
            float k = __expf(-m * lam);
            KT[(size_t)v * T_ + t] = k;
            KMT[(size_t)v * T_ + t] = k * m;
        }
    }
}

// u init, dtT transpose, s1 row sums, zero rec accumulators
__global__ void k_init2(const float* __restrict__ dt, float* __restrict__ u,
                        float* __restrict__ dtT, float* __restrict__ s1,
                        float* __restrict__ recSE, float* __restrict__ recSXL,
                        float* __restrict__ recSX) {
    int i = blockIdx.x * 256 + threadIdx.x;
    if (i < T_ * B_) {
        u[i] = 1.0f / T_;
        int t = i / B_, b = i % B_;
        dtT[i] = dt[(size_t)b * T_ + t];
    }
    if (i < B_) {
        float s = 0.f;
        for (int t = 0; t < T_; ++t) s += dt[(size_t)i * T_ + t];
        s1[i] = s;
        recSE[i] = 0.f; recSXL[i] = 0.f; recSX[i] = 0.f;
    }
}

// bwT[v*B+b] = dw[b*V+v]  (tiled transpose)
__global__ void k_transpose(const float* __restrict__ in, float* __restrict__ outT) {
    __shared__ float tile[32][33];
    int v0 = blockIdx.x * 32, b0 = blockIdx.y * 32;
    int tx = threadIdx.x, ty = threadIdx.y;
    for (int j = 0; j < 4; ++j)
        tile[ty + 8 * j][tx] = in[(size_t)(b0 + ty + 8 * j) * V_ + v0 + tx];
    __syncthreads();
    for (int j = 0; j < 4; ++j)
        outT[(size_t)(v0 + ty + 8 * j) * B_ + b0 + tx] = tile[tx][ty + 8 * j];
}

// Fused: vv = bwT[v,b] / sum_t Kden[v,t]*u[t,b];  acc[t] += Kacc[v,t]*vv
// part[c][t][b] = acc[t] over the chunk's v range.
// __launch_bounds__(256,2): cap VGPRs at 256 so ur[100]+acc[100] stay in
// registers (R0's 64-VGPR build spilled both -> 4.3 GB scratch traffic).
__global__ __launch_bounds__(256, 2) void k_F(const float* __restrict__ Kden,
                                              const float* __restrict__ Kacc,
                                              const float* __restrict__ u,
                                              const float* __restrict__ bwT,
                                              float* __restrict__ part) {
    int b = blockIdx.x * 256 + threadIdx.x;
    int c = blockIdx.y;
    int v0 = c * CH;
    int v1 = min(V_, v0 + CH);
    float ur[T_];
#pragma unroll
    for (int t = 0; t < T_; ++t) ur[t] = u[(size_t)t * B_ + b];
    float acc[T_];
#pragma unroll
    for (int t = 0; t < T_; ++t) acc[t] = 0.f;

    float bwv = bwT[(size_t)v0 * B_ + b];   // software prefetch (1 deep)
    for (int v = v0; v < v1; ++v) {
        float bw_next = (v + 1 < v1) ? bwT[(size_t)(v + 1) * B_ + b] : 0.f;
        const float* kd = Kden + (size_t)v * T_;
        float d0 = 0.f, d1 = 0.f, d2 = 0.f, d3 = 0.f;
#pragma unroll
        for (int t = 0; t < T_; t += 4) {
            d0 += kd[t] * ur[t];
            d1 += kd[t + 1] * ur[t + 1];
            d2 += kd[t + 2] * ur[t + 2];
            d3 += kd[t + 3] * ur[t + 3];
        }
        float vv = bwv / ((d0 + d1) + (d2 + d3));
        const float* ka = Kacc + (size_t)v * T_;
#pragma unroll
        for (int t = 0; t < T_; ++t) acc[t] += ka[t] * vv;
        bwv = bw_next;
    }
#pragma unroll
    for (int t = 0; t < T_; ++t)
        part[((size_t)c * T_ + t) * B_ + b] = acc[t];
}

// reduce partials; mode 0: out = dtT/sum (u update); mode 1: out = sum (kmv)
__global__ void k_B2(const float* __restrict__ part, const float* __restrict__ dtT,
                     float* __restrict__ out, int mode) {
    int i = blockIdx.x * 256 + threadIdx.x;
    if (i >= T_ * B_) return;
    float s = 0.f;
    for (int c = 0; c < NC; ++c) s += part[(size_t)c * T_ * B_ + i];
    out[i] = mode ? s : dtT[i] / s;
}

// div[b] = sum_t u[t,b]*kmv[t,b]
__global__ void k_div(const float* __restrict__ u, const float* __restrict__ kmv,
                      float* __restrict__ divb) {
    int b = blockIdx.x * 256 + threadIdx.x;
    if (b >= B_) return;
    float s = 0.f;
    for (int t = 0; t < T_; ++t) s += u[(size_t)t * B_ + b] * kmv[(size_t)t * B_ + b];
    divb[b] = s;
}

// reconstruction-loss accumulators: per b, sum over v of exp(logit), logit*x, x
__global__ __launch_bounds__(256, 2) void k_rec(const float* __restrict__ M,
                                                const float* __restrict__ dt,
                                                const float* __restrict__ x,
                                                const float* __restrict__ s1,
                                                float* __restrict__ recSE,
                                                float* __restrict__ recSXL,
                                                float* __restrict__ recSX) {
    int v = blockIdx.x * 256 + threadIdx.x;
    int b0 = blockIdx.y * 256;
    bool act = v < V_;
    float Mreg[T_];
#pragma unroll
    for (int t = 0; t < T_; ++t) Mreg[t] = act ? M[(size_t)t * V_ + v] : 0.f;
    for (int bb = 0; bb < 256; ++bb) {
        int b = b0 + bb;
        const float* dtr = dt + (size_t)b * T_;
        float g0 = 0.f, g1 = 0.f, g2 = 0.f, g3 = 0.f;
#pragma unroll
        for (int t = 0; t < T_; t += 4) {
            g0 += dtr[t] * Mreg[t];
            g1 += dtr[t + 1] * Mreg[t + 1];
            g2 += dtr[t + 2] * Mreg[t + 2];
            g3 += dtr[t + 3] * Mreg[t + 3];
        }
        float logit = s1[b] - ((g0 + g1) + (g2 + g3));
        float xv = act ? x[(size_t)b * V_ + v] : 0.f;
        float e = act ? __expf(logit) : 0.f;
        float r0 = e, r1 = logit * xv, r2 = xv;
#pragma unroll
        for (int off = 32; off > 0; off >>= 1) {
            r0 += __shfl_down(r0, off, 64);
            r1 += __shfl_down(r1, off, 64);
            r2 += __shfl_down(r2, off, 64);
        }
        if ((threadIdx.x & 63) == 0) {
            atomicAdd(&recSE[b], r0);
            atomicAdd(&recSXL[b], r1);
            atomicAdd(&recSX[b], r2);
        }
    }
}

__global__ void k_final(const float* __restrict__ divb, const float* __restrict__ recSE,
                        const float* __restrict__ recSXL, const float* __restrict__ recSX,
                        const int* __restrict__ wptr, float* __restrict__ out) {
    __shared__ float sA[256], sB[256];
    int tid = threadIdx.x;
    float accS = 0.f, accR = 0.f;
    for (int b = tid; b < B_; b += 256) {
        accS += divb[b];
        accR += recSXL[b] - logf(recSE[b]) * recSX[b];
    }
    sA[tid] = accS; sB[tid] = accR;
    __syncthreads();
    for (int s = 128; s > 0; s >>= 1) {
        if (tid < s) { sA[tid] += sA[tid + s]; sB[tid] += sB[tid + s]; }
        __syncthreads();
    }
    if (tid == 0) {
        float sh = sA[0] / (float)B_;
        float rec = -sB[0] / (float)B_;
        out[0] = rec;
        out[1] = sh;
        out[2] = (float)(*wptr) * rec + sh;
    }
}

extern "C" void kernel_launch(void* const* d_in, const int* in_sizes, int n_in,
                              void* d_out, int out_size, void* d_ws, size_t ws_size,
                              hipStream_t stream) {
    const float* x  = (const float*)d_in[0];
    const float* dt = (const float*)d_in[1];
    const float* dw = (const float*)d_in[2];
    const float* M  = (const float*)d_in[3];
    const int* alpha = (const int*)d_in[5];
    const int* wrec  = (const int*)d_in[6];
    float* out = (float*)d_out;

    float* ws = (float*)d_ws;
    float* KT     = ws;                       // 2,000,000
    float* KMT    = KT + 2000000;             // 2,000,000
    float* dtT    = KMT + 2000000;            // 204,800
    float* u      = dtT + 204800;             // 204,800
    float* s1     = u + 204800;               // 2,048
    float* recSE  = s1 + 2048;                // 2,048
    float* recSXL = recSE + 2048;             // 2,048
    float* recSX  = recSXL + 2048;            // 2,048
    float* divb   = recSX + 2048;             // 2,048
    float* kmv    = divb + 2048;              // 204,800
    float* part   = kmv + 204800;             // 64*100*2048 = 13,107,200
    float* bwT    = part + (size_t)NC * T_ * B_;    // 40,960,000

    dim3 blk32(32, 8);
    k_initK<<<dim3(625, 4), blk32, 0, stream>>>(M, alpha, KT, KMT);
    k_init2<<<(T_ * B_ + 255) / 256, 256, 0, stream>>>(dt, u, dtT, s1, recSE, recSXL, recSX);
    k_transpose<<<dim3(625, 64), blk32, 0, stream>>>(dw, bwT);
    k_rec<<<dim3(79, 8), 256, 0, stream>>>(M, dt, x, s1, recSE, recSXL, recSX);

    for (int it = 0; it < 50; ++it) {
        k_F<<<dim3(8, NC), 256, 0, stream>>>(KT, KT, u, bwT, part);
        k_B2<<<(T_ * B_ + 255) / 256, 256, 0, stream>>>(part, dtT, u, 0);
    }
    k_F<<<dim3(8, NC), 256, 0, stream>>>(KT, KMT, u, bwT, part);
    k_B2<<<(T_ * B_ + 255) / 256, 256, 0, stream>>>(part, dtT, kmv, 1);
    k_div<<<(B_ + 255) / 256, 256, 0, stream>>>(u, kmv, divb);
    k_final<<<1, 256, 0, stream>>>(divb, recSE, recSXL, recSX, wrec, out);
}

// Round 3
// 7654.507 us; speedup vs baseline: 11.2880x; 3.0181x over previous
//
#include <hip/hip_runtime.h>
#include <math.h>

#define B_   2048
#define T_   100
#define V_   20000
#define VP   20480
#define KP   128
#define TP   112
#define NC2  32
#define CH2  640

typedef short s8v __attribute__((ext_vector_type(8)));
typedef short s4v __attribute__((ext_vector_type(4)));
typedef float f4  __attribute__((ext_vector_type(4)));

__device__ __forceinline__ short f2bf(float f) {
    unsigned u = __builtin_bit_cast(unsigned, f);
    u += 0x7fffu + ((u >> 16) & 1u);
    return (short)(u >> 16);
}
__device__ __forceinline__ float bf2f(short h) {
    unsigned u = ((unsigned)(unsigned short)h) << 16;
    return __builtin_bit_cast(float, u);
}
#define MFMA(a,b,c) __builtin_amdgcn_mfma_f32_16x16x32_bf16((a),(b),(c),0,0,0)

// A1[v][t] = exp(-lam*M[t][v]) bf16 (t-pad to 128, v-pad to VP, zeros)
// W1[v][t] = 1 - M[t][v] bf16 (same pads)
__global__ void k_initKT(const float* __restrict__ M, const int* __restrict__ alpha,
                         short* __restrict__ A1, short* __restrict__ W1) {
    __shared__ float tile[32][33];
    float lam = (float)(*alpha);
    int v0 = blockIdx.x * 32, t0 = blockIdx.y * 32;
    int tx = threadIdx.x, ty = threadIdx.y;
    for (int j = 0; j < 4; ++j) {
        int t = t0 + ty + 8 * j, v = v0 + tx;
        tile[ty + 8 * j][tx] = (t < T_ && v < V_) ? M[(size_t)t * V_ + v] : 0.f;
    }
    __syncthreads();
    for (int j = 0; j < 4; ++j) {
        int t = t0 + tx, v = v0 + ty + 8 * j;
        float m = tile[tx][ty + 8 * j];
        bool valid = (t < T_) && (v < V_);
        A1[(size_t)v * KP + t] = valid ? f2bf(__expf(-m * lam)) : (short)0;
        W1[(size_t)v * KP + t] = valid ? f2bf(1.f - m) : (short)0;
    }
}

// A2[t][v] = K bf16, A2M[t][v] = K*M bf16; [TP][VP] zero-padded
__global__ void k_initA2(const float* __restrict__ M, const int* __restrict__ alpha,
                         short* __restrict__ A2, short* __restrict__ A2M) {
    float lam = (float)(*alpha);
    size_t id = (size_t)blockIdx.x * 256 + threadIdx.x;   // < TP*VP
    int t = (int)(id / VP), v = (int)(id % VP);
    bool valid = (t < T_) && (v < V_);
    float m = valid ? M[(size_t)t * V_ + v] : 0.f;
    float k = valid ? __expf(-m * lam) : 0.f;
    A2[id]  = valid ? f2bf(k) : (short)0;
    A2M[id] = valid ? f2bf(k * m) : (short)0;
}

// uT init (1/T in bf16, pads zero) + zero rec accumulators
__global__ void k_init0(short* __restrict__ uTbf, float* __restrict__ recSE,
                        float* __restrict__ recSXL, float* __restrict__ recSX) {
    int id = blockIdx.x * 256 + threadIdx.x;   // < B_*KP
    int t = id & (KP - 1);
    uTbf[id] = (t < T_) ? f2bf(0.01f) : (short)0;
    if (id < B_) { recSE[id] = 0.f; recSXL[id] = 0.f; recSX[id] = 0.f; }
}

// dwbf[b][v] = bf16(dw[b][v]) flat
__global__ void k_castdw(const float* __restrict__ dw, short* __restrict__ dwbf) {
    size_t base = ((size_t)blockIdx.x * 256 + threadIdx.x) * 8;   // < B_*V_
    f4 x0 = *(const f4*)(dw + base);
    f4 x1 = *(const f4*)(dw + base + 4);
    s8v o;
    o[0]=f2bf(x0[0]); o[1]=f2bf(x0[1]); o[2]=f2bf(x0[2]); o[3]=f2bf(x0[3]);
    o[4]=f2bf(x1[0]); o[5]=f2bf(x1[1]); o[6]=f2bf(x1[2]); o[7]=f2bf(x1[3]);
    *(s8v*)(dwbf + base) = o;
}

// dtbf[b][t] bf16, t-pad 128
__global__ void k_castdt(const float* __restrict__ dt, short* __restrict__ dtbf) {
    int id = blockIdx.x * 256 + threadIdx.x;   // < B_*KP
    int b = id >> 7, t = id & (KP - 1);
    dtbf[id] = (t < T_) ? f2bf(dt[(size_t)b * T_ + t]) : (short)0;
}

// GEMM1: den[v,b] = A1[v,:] @ uT[b,:]^T ; vT[b][v] = dwbf[b][v]/den (bf16)
__global__ __launch_bounds__(256, 2) void k_G1(const short* __restrict__ A1,
                                               const short* __restrict__ uT,
                                               const short* __restrict__ dwbf,
                                               short* __restrict__ vT) {
    __shared__ float lds[128 * 132];   // [b][v], stride 132 (bank-spread, 16B-aligned)
    int tid = threadIdx.x;
    int wave = tid >> 6, lane = tid & 63, q = lane >> 4, l16 = lane & 15;
    int v0 = blockIdx.x * 128, b0 = blockIdx.y * 128;
    f4 acc[2][8];
#pragma unroll
    for (int rv = 0; rv < 2; ++rv)
#pragma unroll
        for (int cb = 0; cb < 8; ++cb) acc[rv][cb] = (f4)0.f;
#pragma unroll
    for (int ks = 0; ks < 4; ++ks) {
        int ko = ks * 32 + q * 8;
        s8v a0 = *(const s8v*)(A1 + (size_t)(v0 + wave * 32 + l16) * KP + ko);
        s8v a1 = *(const s8v*)(A1 + (size_t)(v0 + wave * 32 + 16 + l16) * KP + ko);
#pragma unroll
        for (int cb = 0; cb < 8; ++cb) {
            s8v bb = *(const s8v*)(uT + (size_t)(b0 + cb * 16 + l16) * KP + ko);
            acc[0][cb] = MFMA(a0, bb, acc[0][cb]);
            acc[1][cb] = MFMA(a1, bb, acc[1][cb]);
        }
    }
    // D layout: row(v) = q*4+r, col(b) = l16 -> store transposed via LDS
#pragma unroll
    for (int rv = 0; rv < 2; ++rv)
#pragma unroll
        for (int cb = 0; cb < 8; ++cb) {
            int bl = cb * 16 + l16;
            int vl = wave * 32 + rv * 16 + q * 4;
            *(f4*)(&lds[bl * 132 + vl]) = acc[rv][cb];
        }
    __syncthreads();
#pragma unroll
    for (int i = 0; i < 16; ++i) {
        int chunk = i * 256 + tid;        // 4096 chunks of 4 v
        int bl = chunk >> 5, vc = chunk & 31;
        int vg = v0 + vc * 4, bg = b0 + bl;
        f4 den = *(f4*)(&lds[bl * 132 + vc * 4]);
        s4v o;
        if (vg < V_) {
            s4v w = *(const s4v*)(dwbf + (size_t)bg * V_ + vg);
#pragma unroll
            for (int j = 0; j < 4; ++j) o[j] = f2bf(bf2f(w[j]) / den[j]);
        } else {
            o[0] = 0; o[1] = 0; o[2] = 0; o[3] = 0;
        }
        *(s4v*)(vT + (size_t)bg * VP + vg) = o;
    }
}

// GEMM2 split-K: part2[c][b][t] = sum_{v in chunk c} A2[t][v]*vT[b][v]
__global__ __launch_bounds__(256, 2) void k_G2(const short* __restrict__ A2,
                                               const short* __restrict__ vT,
                                               float* __restrict__ part2) {
    int tid = threadIdx.x;
    int wave = tid >> 6, lane = tid & 63, q = lane >> 4, l16 = lane & 15;
    int b0 = blockIdx.x * 128;
    int c = blockIdx.y;
    int vbase = c * CH2;
    f4 acc[7][2];
#pragma unroll
    for (int tt = 0; tt < 7; ++tt) { acc[tt][0] = (f4)0.f; acc[tt][1] = (f4)0.f; }
    for (int ks = 0; ks < CH2 / 32; ++ks) {
        int ko = vbase + ks * 32 + q * 8;
        s8v bb0 = *(const s8v*)(vT + (size_t)(b0 + wave * 32 + l16) * VP + ko);
        s8v bb1 = *(const s8v*)(vT + (size_t)(b0 + wave * 32 + 16 + l16) * VP + ko);
#pragma unroll
        for (int tt = 0; tt < 7; ++tt) {
            s8v a = *(const s8v*)(A2 + (size_t)(tt * 16 + l16) * VP + ko);
            acc[tt][0] = MFMA(a, bb0, acc[tt][0]);
            acc[tt][1] = MFMA(a, bb1, acc[tt][1]);
        }
    }
#pragma unroll
    for (int tt = 0; tt < 7; ++tt)
#pragma unroll
        for (int cb = 0; cb < 2; ++cb) {
            int bg = b0 + wave * 32 + cb * 16 + l16;
            int t4 = tt * 16 + q * 4;
            *(f4*)(part2 + ((size_t)c * B_ + bg) * TP + t4) = acc[tt][cb];
        }
}

// reduce partials; mode 0: u = dt/sum -> uf fp32 + uTbf bf16; mode 1: kmvf = sum
__global__ void k_R(const float* __restrict__ part2, const float* __restrict__ dt,
                    float* __restrict__ uf, short* __restrict__ uTbf,
                    float* __restrict__ kmvf, int mode) {
    int id = blockIdx.x * 256 + threadIdx.x;   // < B_*28
    int b = id / 28, t4 = (id % 28) * 4;
    f4 s = (f4)0.f;
    for (int c = 0; c < NC2; ++c)
        s += *(const f4*)(part2 + ((size_t)c * B_ + b) * TP + t4);
    if (mode == 0) {
#pragma unroll
        for (int j = 0; j < 4; ++j) {
            int t = t4 + j;
            float v = (t < T_) ? dt[(size_t)b * T_ + t] / s[j] : 0.f;
            uf[(size_t)b * TP + t] = v;
            uTbf[(size_t)b * KP + t] = f2bf(v);
        }
    } else {
#pragma unroll
        for (int j = 0; j < 4; ++j) kmvf[(size_t)b * TP + t4 + j] = s[j];
    }
}

// rec loss via MFMA: logits = dt @ (1-M); accumulate SE/SXL/SX per b
__global__ __launch_bounds__(256, 2) void k_rec(const short* __restrict__ dtbf,
                                                const short* __restrict__ W1,
                                                const float* __restrict__ x,
                                                float* __restrict__ recSE,
                                                float* __restrict__ recSXL,
                                                float* __restrict__ recSX) {
    int tid = threadIdx.x;
    int wave = tid >> 6, lane = tid & 63, q = lane >> 4, l16 = lane & 15;
    int v0 = blockIdx.x * 256;
    int b0 = blockIdx.y * 64 + wave * 16;
    f4 acc[16];
#pragma unroll
    for (int vt = 0; vt < 16; ++vt) acc[vt] = (f4)0.f;
#pragma unroll
    for (int ks = 0; ks < 4; ++ks) {
        int ko = ks * 32 + q * 8;
        s8v a = *(const s8v*)(dtbf + (size_t)(b0 + l16) * KP + ko);
#pragma unroll
        for (int vt = 0; vt < 16; ++vt) {
            s8v bb = *(const s8v*)(W1 + (size_t)(v0 + vt * 16 + l16) * KP + ko);
            acc[vt] = MFMA(a, bb, acc[vt]);
        }
    }
    float se[4] = {0.f, 0.f, 0.f, 0.f}, sxl[4] = {0.f, 0.f, 0.f, 0.f}, sx[4] = {0.f, 0.f, 0.f, 0.f};
#pragma unroll
    for (int vt = 0; vt < 16; ++vt) {
        int v = v0 + vt * 16 + l16;
        bool act = v < V_;
#pragma unroll
        for (int r = 0; r < 4; ++r) {
            float logit = acc[vt][r];
            float xv = act ? x[(size_t)(b0 + q * 4 + r) * V_ + v] : 0.f;
            se[r]  += act ? __expf(logit) : 0.f;
            sxl[r] += logit * xv;
            sx[r]  += xv;
        }
    }
#pragma unroll
    for (int m = 1; m < 16; m <<= 1)
#pragma unroll
        for (int r = 0; r < 4; ++r) {
            se[r]  += __shfl_xor(se[r], m, 64);
            sxl[r] += __shfl_xor(sxl[r], m, 64);
            sx[r]  += __shfl_xor(sx[r], m, 64);
        }
    if (l16 == 0) {
#pragma unroll
        for (int r = 0; r < 4; ++r) {
            int b = b0 + q * 4 + r;
            atomicAdd(&recSE[b], se[r]);
            atomicAdd(&recSXL[b], sxl[r]);
            atomicAdd(&recSX[b], sx[r]);
        }
    }
}

__global__ void k_div(const float* __restrict__ uf, const float* __restrict__ kmvf,
                      float* __restrict__ divb) {
    int b = blockIdx.x * 256 + threadIdx.x;
    if (b >= B_) return;
    float s = 0.f;
    for (int t = 0; t < TP; ++t) s += uf[(size_t)b * TP + t] * kmvf[(size_t)b * TP + t];
    divb[b] = s;
}

__global__ void k_final(const float* __restrict__ divb, const float* __restrict__ recSE,
                        const float* __restrict__ recSXL, const float* __restrict__ recSX,
                        const int* __restrict__ wptr, float* __restrict__ out) {
    __shared__ float sA[256], sB[256];
    int tid = threadIdx.x;
    float accS = 0.f, accR = 0.f;
    for (int b = tid; b < B_; b += 256) {
        accS += divb[b];
        accR += recSXL[b] - logf(recSE[b]) * recSX[b];
    }
    sA[tid] = accS; sB[tid] = accR;
    __syncthreads();
    for (int s = 128; s > 0; s >>= 1) {
        if (tid < s) { sA[tid] += sA[tid + s]; sB[tid] += sB[tid + s]; }
        __syncthreads();
    }
    if (tid == 0) {
        float sh = sA[0] / (float)B_;
        float rec = -sB[0] / (float)B_;
        out[0] = rec;
        out[1] = sh;
        out[2] = (float)(*wptr) * rec + sh;
    }
}

extern "C" void kernel_launch(void* const* d_in, const int* in_sizes, int n_in,
                              void* d_out, int out_size, void* d_ws, size_t ws_size,
                              hipStream_t stream) {
    const float* x  = (const float*)d_in[0];
    const float* dt = (const float*)d_in[1];
    const float* dw = (const float*)d_in[2];
    const float* M  = (const float*)d_in[3];
    const int* alpha = (const int*)d_in[5];
    const int* wrec  = (const int*)d_in[6];
    float* out = (float*)d_out;

    char* p = (char*)d_ws;
    short* A1   = (short*)p; p += (size_t)VP * KP * 2;
    short* W1   = (short*)p; p += (size_t)VP * KP * 2;
    short* A2   = (short*)p; p += (size_t)TP * VP * 2;
    short* A2M  = (short*)p; p += (size_t)TP * VP * 2;
    short* uTbf = (short*)p; p += (size_t)B_ * KP * 2;
    short* dtbf = (short*)p; p += (size_t)B_ * KP * 2;
    short* dwbf = (short*)p; p += (size_t)B_ * V_ * 2;
    short* vT   = (short*)p; p += (size_t)B_ * VP * 2;
    float* part2 = (float*)p; p += (size_t)NC2 * B_ * TP * 4;
    float* uf    = (float*)p; p += (size_t)B_ * TP * 4;
    float* kmvf  = (float*)p; p += (size_t)B_ * TP * 4;
    float* recSE  = (float*)p; p += B_ * 4;
    float* recSXL = (float*)p; p += B_ * 4;
    float* recSX  = (float*)p; p += B_ * 4;
    float* divb   = (float*)p; p += B_ * 4;

    k_initKT<<<dim3(VP / 32, 4), dim3(32, 8), 0, stream>>>(M, alpha, A1, W1);
    k_initA2<<<(TP * VP) / 256, 256, 0, stream>>>(M, alpha, A2, A2M);
    k_init0<<<(B_ * KP) / 256, 256, 0, stream>>>(uTbf, recSE, recSXL, recSX);
    k_castdw<<<(B_ * V_) / (256 * 8), 256, 0, stream>>>(dw, dwbf);
    k_castdt<<<(B_ * KP) / 256, 256, 0, stream>>>(dt, dtbf);
    k_rec<<<dim3(79, B_ / 64), 256, 0, stream>>>(dtbf, W1, x, recSE, recSXL, recSX);

    for (int it = 0; it < 50; ++it) {
        k_G1<<<dim3(VP / 128, B_ / 128), 256, 0, stream>>>(A1, uTbf, dwbf, vT);
        k_G2<<<dim3(B_ / 128, NC2), 256, 0, stream>>>(A2, vT, part2);
        k_R<<<(B_ * 28) / 256, 256, 0, stream>>>(part2, dt, uf, uTbf, kmvf, 0);
    }
    k_G1<<<dim3(VP / 128, B_ / 128), 256, 0, stream>>>(A1, uTbf, dwbf, vT);
    k_G2<<<dim3(B_ / 128, NC2), 256, 0, stream>>>(A2M, vT, part2);
    k_R<<<(B_ * 28) / 256, 256, 0, stream>>>(part2, dt, uf, uTbf, kmvf, 1);
    k_div<<<B_ / 256, 256, 0, stream>>>(uf, kmvf, divb);
    k_final<<<1, 256, 0, stream>>>(divb, recSE, recSXL, recSX, wrec, out);
}

// Round 4
// 6517.342 us; speedup vs baseline: 13.2575x; 1.1745x over previous
//
#include <hip/hip_runtime.h>
#include <math.h>

#define B_   2048
#define T_   100
#define V_   20000
#define VP   20480
#define KP   128
#define TP   112
#define NC2  32
#define CH2  640
#define LDV  72    // vv LDS row stride (shorts): 144B = 16B-aligned, 2-way banks (free)

typedef short s8v __attribute__((ext_vector_type(8)));
typedef short s4v __attribute__((ext_vector_type(4)));
typedef float f4  __attribute__((ext_vector_type(4)));

__device__ __forceinline__ short f2bf(float f) {
    unsigned u = __builtin_bit_cast(unsigned, f);
    u += 0x7fffu + ((u >> 16) & 1u);
    return (short)(u >> 16);
}
__device__ __forceinline__ float bf2f(short h) {
    unsigned u = ((unsigned)(unsigned short)h) << 16;
    return __builtin_bit_cast(float, u);
}
#define MFMA(a,b,c) __builtin_amdgcn_mfma_f32_16x16x32_bf16((a),(b),(c),0,0,0)

// A1[v][t] = exp(-lam*M[t][v]) bf16 (t-pad to 128, v-pad to VP, zeros)
// W1[v][t] = 1 - M[t][v] bf16 (same pads)
__global__ void k_initKT(const float* __restrict__ M, const int* __restrict__ alpha,
                         short* __restrict__ A1, short* __restrict__ W1) {
    __shared__ float tile[32][33];
    float lam = (float)(*alpha);
    int v0 = blockIdx.x * 32, t0 = blockIdx.y * 32;
    int tx = threadIdx.x, ty = threadIdx.y;
    for (int j = 0; j < 4; ++j) {
        int t = t0 + ty + 8 * j, v = v0 + tx;
        tile[ty + 8 * j][tx] = (t < T_ && v < V_) ? M[(size_t)t * V_ + v] : 0.f;
    }
    __syncthreads();
    for (int j = 0; j < 4; ++j) {
        int t = t0 + tx, v = v0 + ty + 8 * j;
        float m = tile[tx][ty + 8 * j];
        bool valid = (t < T_) && (v < V_);
        A1[(size_t)v * KP + t] = valid ? f2bf(__expf(-m * lam)) : (short)0;
        W1[(size_t)v * KP + t] = valid ? f2bf(1.f - m) : (short)0;
    }
}

// A2[t][v] = K bf16, A2M[t][v] = K*M bf16; [TP][VP] zero-padded
__global__ void k_initA2(const float* __restrict__ M, const int* __restrict__ alpha,
                         short* __restrict__ A2, short* __restrict__ A2M) {
    float lam = (float)(*alpha);
    size_t id = (size_t)blockIdx.x * 256 + threadIdx.x;   // < TP*VP
    int t = (int)(id / VP), v = (int)(id % VP);
    bool valid = (t < T_) && (v < V_);
    float m = valid ? M[(size_t)t * V_ + v] : 0.f;
    float k = valid ? __expf(-m * lam) : 0.f;
    A2[id]  = valid ? f2bf(k) : (short)0;
    A2M[id] = valid ? f2bf(k * m) : (short)0;
}

// uT init (1/T in bf16, pads zero) + zero rec accumulators
__global__ void k_init0(short* __restrict__ uTbf, float* __restrict__ recSE,
                        float* __restrict__ recSXL, float* __restrict__ recSX) {
    int id = blockIdx.x * 256 + threadIdx.x;   // < B_*KP
    int t = id & (KP - 1);
    uTbf[id] = (t < T_) ? f2bf(0.01f) : (short)0;
    if (id < B_) { recSE[id] = 0.f; recSXL[id] = 0.f; recSX[id] = 0.f; }
}

// dwbf[b][v] = bf16(dw[b][v]) flat
__global__ void k_castdw(const float* __restrict__ dw, short* __restrict__ dwbf) {
    size_t base = ((size_t)blockIdx.x * 256 + threadIdx.x) * 8;   // < B_*V_
    f4 x0 = *(const f4*)(dw + base);
    f4 x1 = *(const f4*)(dw + base + 4);
    s8v o;
    o[0]=f2bf(x0[0]); o[1]=f2bf(x0[1]); o[2]=f2bf(x0[2]); o[3]=f2bf(x0[3]);
    o[4]=f2bf(x1[0]); o[5]=f2bf(x1[1]); o[6]=f2bf(x1[2]); o[7]=f2bf(x1[3]);
    *(s8v*)(dwbf + base) = o;
}

// dtbf[b][t] bf16, t-pad 128
__global__ void k_castdt(const float* __restrict__ dt, short* __restrict__ dtbf) {
    int id = blockIdx.x * 256 + threadIdx.x;   // < B_*KP
    int b = id >> 7, t = id & (KP - 1);
    dtbf[id] = (t < T_) ? f2bf(dt[(size_t)b * T_ + t]) : (short)0;
}

// Fused Sinkhorn iteration kernel:
//   per v-strip (64): den^T[b][v] = uT @ A1^T  (MFMA, D row=b col=v)
//                     vv = dw/den -> bf16 -> LDS [b][v] (double-buffered)
//                     C2[t][b] += A2acc[:,strip] @ vv^T (B-frags from LDS)
//   part2[c][b][t] written once at the end (split-K over 32 chunks).
__global__ __launch_bounds__(256, 2) void k_GF(const short* __restrict__ A1,
                                               const short* __restrict__ A2acc,
                                               const short* __restrict__ uT,
                                               const short* __restrict__ dwbf,
                                               float* __restrict__ part2) {
    __shared__ short vv[2][128 * LDV];
    int tid = threadIdx.x;
    int wave = tid >> 6, lane = tid & 63, q = lane >> 4, l16 = lane & 15;
    int b0 = blockIdx.x * 128;
    int c  = blockIdx.y;
    int v0 = c * CH2;
    int bw = b0 + wave * 32;

    // hoisted A-frags (uT rows; strip-invariant): [cb][ks]
    s8v au[2][4];
#pragma unroll
    for (int cb = 0; cb < 2; ++cb)
#pragma unroll
        for (int ks = 0; ks < 4; ++ks)
            au[cb][ks] = *(const s8v*)(uT + (size_t)(bw + cb * 16 + l16) * KP + ks * 32 + q * 8);

    f4 acc2[7][2];
#pragma unroll
    for (int tt = 0; tt < 7; ++tt) { acc2[tt][0] = (f4)0.f; acc2[tt][1] = (f4)0.f; }

    for (int s = 0; s < 10; ++s) {
        int vs = v0 + s * 64;
        // ---- phase 1: den^T [32 b x 64 v] ----
        f4 acc1[2][4];
#pragma unroll
        for (int cb = 0; cb < 2; ++cb)
#pragma unroll
            for (int vt = 0; vt < 4; ++vt) acc1[cb][vt] = (f4)0.f;
#pragma unroll
        for (int ks = 0; ks < 4; ++ks) {
            int ko = ks * 32 + q * 8;
            s8v bv[4];
#pragma unroll
            for (int vt = 0; vt < 4; ++vt)
                bv[vt] = *(const s8v*)(A1 + (size_t)(vs + vt * 16 + l16) * KP + ko);
#pragma unroll
            for (int cb = 0; cb < 2; ++cb)
#pragma unroll
                for (int vt = 0; vt < 4; ++vt)
                    acc1[cb][vt] = MFMA(au[cb][ks], bv[vt], acc1[cb][vt]);
        }
        // ---- divide + vv -> LDS ----
        short* buf = vv[s & 1];
#pragma unroll
        for (int cb = 0; cb < 2; ++cb)
#pragma unroll
            for (int vt = 0; vt < 4; ++vt) {
                int vg = vs + vt * 16 + l16;
                f4 den = acc1[cb][vt];
#pragma unroll
                for (int r = 0; r < 4; ++r) {
                    int bl = wave * 32 + cb * 16 + q * 4 + r;
                    float val = 0.f;
                    if (vg < V_) {
                        float dwv = bf2f(dwbf[(size_t)(b0 + bl) * V_ + vg]);
                        val = dwv * __builtin_amdgcn_rcpf(den[r]);
                    }
                    buf[bl * LDV + vt * 16 + l16] = f2bf(val);
                }
            }
        __syncthreads();
        // ---- phase 2: C2 += A2acc[:, strip] @ vv^T ----
#pragma unroll
        for (int ks2 = 0; ks2 < 2; ++ks2) {
            int ko = ks2 * 32 + q * 8;
            s8v bb[2];
#pragma unroll
            for (int cb = 0; cb < 2; ++cb)
                bb[cb] = *(const s8v*)(buf + (wave * 32 + cb * 16 + l16) * LDV + ko);
#pragma unroll
            for (int tt = 0; tt < 7; ++tt) {
                s8v a = *(const s8v*)(A2acc + (size_t)(tt * 16 + l16) * VP + vs + ko);
#pragma unroll
                for (int cb = 0; cb < 2; ++cb)
                    acc2[tt][cb] = MFMA(a, bb[cb], acc2[tt][cb]);
            }
        }
    }
#pragma unroll
    for (int tt = 0; tt < 7; ++tt)
#pragma unroll
        for (int cb = 0; cb < 2; ++cb) {
            int bg = bw + cb * 16 + l16;
            *(f4*)(part2 + ((size_t)c * B_ + bg) * TP + tt * 16 + q * 4) = acc2[tt][cb];
        }
}

// reduce partials; mode 0: u = dt/sum -> uf fp32 + uTbf bf16; mode 1: kmvf = sum
__global__ void k_R(const float* __restrict__ part2, const float* __restrict__ dt,
                    float* __restrict__ uf, short* __restrict__ uTbf,
                    float* __restrict__ kmvf, int mode) {
    int id = blockIdx.x * 256 + threadIdx.x;   // < B_*28
    int b = id / 28, t4 = (id % 28) * 4;
    f4 s = (f4)0.f;
    for (int c = 0; c < NC2; ++c)
        s += *(const f4*)(part2 + ((size_t)c * B_ + b) * TP + t4);
    if (mode == 0) {
#pragma unroll
        for (int j = 0; j < 4; ++j) {
            int t = t4 + j;
            float v = (t < T_) ? dt[(size_t)b * T_ + t] / s[j] : 0.f;
            uf[(size_t)b * TP + t] = v;
            uTbf[(size_t)b * KP + t] = f2bf(v);
        }
    } else {
#pragma unroll
        for (int j = 0; j < 4; ++j) kmvf[(size_t)b * TP + t4 + j] = s[j];
    }
}

// rec loss: logits = dt @ (1-M) via MFMA; transpose through LDS; coalesced x reads
__global__ __launch_bounds__(256, 2) void k_rec(const short* __restrict__ dtbf,
                                                const short* __restrict__ W1,
                                                const float* __restrict__ x,
                                                float* __restrict__ recSE,
                                                float* __restrict__ recSXL,
                                                float* __restrict__ recSX) {
    __shared__ float lg[64 * 260];
    int tid = threadIdx.x;
    int wave = tid >> 6, lane = tid & 63, q = lane >> 4, l16 = lane & 15;
    int v0 = blockIdx.x * 256;
    int b0 = blockIdx.y * 64;
    int bw = b0 + wave * 16;
    f4 acc[16];
#pragma unroll
    for (int vt = 0; vt < 16; ++vt) acc[vt] = (f4)0.f;
#pragma unroll
    for (int ks = 0; ks < 4; ++ks) {
        int ko = ks * 32 + q * 8;
        s8v a = *(const s8v*)(dtbf + (size_t)(bw + l16) * KP + ko);
#pragma unroll
        for (int vt = 0; vt < 16; ++vt) {
            s8v bb = *(const s8v*)(W1 + (size_t)(v0 + vt * 16 + l16) * KP + ko);
            acc[vt] = MFMA(a, bb, acc[vt]);
        }
    }
    // D: row=b (q*4+r within wave's 16), col=v (l16) -> LDS [b][v]
#pragma unroll
    for (int vt = 0; vt < 16; ++vt)
#pragma unroll
        for (int r = 0; r < 4; ++r)
            lg[(wave * 16 + q * 4 + r) * 260 + vt * 16 + l16] = acc[vt][r];
    __syncthreads();
    int bl = tid >> 2, seg = tid & 3;
    int bg = b0 + bl;
    float se = 0.f, sxl = 0.f, sx = 0.f;
#pragma unroll
    for (int i = 0; i < 16; ++i) {
        int vl = seg * 64 + i * 4;
        int vg = v0 + vl;
        f4 lo = *(f4*)(&lg[bl * 260 + vl]);
        if (vg + 3 < V_) {
            f4 xv = *(const f4*)(x + (size_t)bg * V_ + vg);
#pragma unroll
            for (int j = 0; j < 4; ++j) {
                se += __expf(lo[j]); sxl += lo[j] * xv[j]; sx += xv[j];
            }
        } else {
#pragma unroll
            for (int j = 0; j < 4; ++j)
                if (vg + j < V_) {
                    float xv = x[(size_t)bg * V_ + vg + j];
                    se += __expf(lo[j]); sxl += lo[j] * xv; sx += xv;
                }
        }
    }
    se  += __shfl_xor(se, 1, 64);  se  += __shfl_xor(se, 2, 64);
    sxl += __shfl_xor(sxl, 1, 64); sxl += __shfl_xor(sxl, 2, 64);
    sx  += __shfl_xor(sx, 1, 64);  sx  += __shfl_xor(sx, 2, 64);
    if (seg == 0) {
        atomicAdd(&recSE[bg], se);
        atomicAdd(&recSXL[bg], sxl);
        atomicAdd(&recSX[bg], sx);
    }
}

__global__ void k_div(const float* __restrict__ uf, const float* __restrict__ kmvf,
                      float* __restrict__ divb) {
    int b = blockIdx.x * 256 + threadIdx.x;
    if (b >= B_) return;
    float s = 0.f;
    for (int t = 0; t < TP; ++t) s += uf[(size_t)b * TP + t] * kmvf[(size_t)b * TP + t];
    divb[b] = s;
}

__global__ void k_final(const float* __restrict__ divb, const float* __restrict__ recSE,
                        const float* __restrict__ recSXL, const float* __restrict__ recSX,
                        const int* __restrict__ wptr, float* __restrict__ out) {
    __shared__ float sA[256], sB[256];
    int tid = threadIdx.x;
    float accS = 0.f, accR = 0.f;
    for (int b = tid; b < B_; b += 256) {
        accS += divb[b];
        accR += recSXL[b] - logf(recSE[b]) * recSX[b];
    }
    sA[tid] = accS; sB[tid] = accR;
    __syncthreads();
    for (int s = 128; s > 0; s >>= 1) {
        if (tid < s) { sA[tid] += sA[tid + s]; sB[tid] += sB[tid + s]; }
        __syncthreads();
    }
    if (tid == 0) {
        float sh = sA[0] / (float)B_;
        float rec = -sB[0] / (float)B_;
        out[0] = rec;
        out[1] = sh;
        out[2] = (float)(*wptr) * rec + sh;
    }
}

extern "C" void kernel_launch(void* const* d_in, const int* in_sizes, int n_in,
                              void* d_out, int out_size, void* d_ws, size_t ws_size,
                              hipStream_t stream) {
    const float* x  = (const float*)d_in[0];
    const float* dt = (const float*)d_in[1];
    const float* dw = (const float*)d_in[2];
    const float* M  = (const float*)d_in[3];
    const int* alpha = (const int*)d_in[5];
    const int* wrec  = (const int*)d_in[6];
    float* out = (float*)d_out;

    char* p = (char*)d_ws;
    short* A1   = (short*)p; p += (size_t)VP * KP * 2;
    short* W1   = (short*)p; p += (size_t)VP * KP * 2;
    short* A2   = (short*)p; p += (size_t)TP * VP * 2;
    short* A2M  = (short*)p; p += (size_t)TP * VP * 2;
    short* uTbf = (short*)p; p += (size_t)B_ * KP * 2;
    short* dtbf = (short*)p; p += (size_t)B_ * KP * 2;
    short* dwbf = (short*)p; p += (size_t)B_ * V_ * 2;
    float* part2 = (float*)p; p += (size_t)NC2 * B_ * TP * 4;
    float* uf    = (float*)p; p += (size_t)B_ * TP * 4;
    float* kmvf  = (float*)p; p += (size_t)B_ * TP * 4;
    float* recSE  = (float*)p; p += B_ * 4;
    float* recSXL = (float*)p; p += B_ * 4;
    float* recSX  = (float*)p; p += B_ * 4;
    float* divb   = (float*)p; p += B_ * 4;

    k_initKT<<<dim3(VP / 32, 4), dim3(32, 8), 0, stream>>>(M, alpha, A1, W1);
    k_initA2<<<(TP * VP) / 256, 256, 0, stream>>>(M, alpha, A2, A2M);
    k_init0<<<(B_ * KP) / 256, 256, 0, stream>>>(uTbf, recSE, recSXL, recSX);
    k_castdw<<<(B_ * V_) / (256 * 8), 256, 0, stream>>>(dw, dwbf);
    k_castdt<<<(B_ * KP) / 256, 256, 0, stream>>>(dt, dtbf);
    k_rec<<<dim3(79, B_ / 64), 256, 0, stream>>>(dtbf, W1, x, recSE, recSXL, recSX);

    for (int it = 0; it < 50; ++it) {
        k_GF<<<dim3(B_ / 128, NC2), 256, 0, stream>>>(A1, A2, uTbf, dwbf, part2);
        k_R<<<(B_ * 28) / 256, 256, 0, stream>>>(part2, dt, uf, uTbf, kmvf, 0);
    }
    k_GF<<<dim3(B_ / 128, NC2), 256, 0, stream>>>(A1, A2M, uTbf, dwbf, part2);
    k_R<<<(B_ * 28) / 256, 256, 0, stream>>>(part2, dt, uf, uTbf, kmvf, 1);
    k_div<<<B_ / 256, 256, 0, stream>>>(uf, kmvf, divb);
    k_final<<<1, 256, 0, stream>>>(divb, recSE, recSXL, recSX, wrec, out);
}